// Round 17
// baseline (685.075 us; speedup 1.0000x reference)
//
#include <hip/hip_runtime.h>
#include <hip/hip_bf16.h>
#include <stdint.h>

#define Bq 256
#define Sq 49
#define Dq 1024
#define Hq 2
#define HDq 512
#define Mq (Bq*Sq)        // 12544
#define KHEADq (Sq*Dq)    // 50176
#define STq 3072          // fused qkv row stride

typedef unsigned short u16;
typedef short bf16x8 __attribute__((ext_vector_type(8)));
typedef float f32x4 __attribute__((ext_vector_type(4)));

__device__ inline u16 f2bf(float f){
  union { float f; uint32_t u; } c; c.f = f;
  uint32_t r = c.u + 0x7FFFu + ((c.u >> 16) & 1u);
  return (u16)(r >> 16);
}
__device__ inline float bf2f(u16 h){
  union { uint32_t u; float f; } c; c.u = ((uint32_t)h) << 16;
  return c.f;
}

#define GLOAD_LDS16(gp, lp) \
  __builtin_amdgcn_global_load_lds((__attribute__((address_space(1))) void*)(gp), \
                                   (__attribute__((address_space(3))) void*)(lp), 16, 0, 0)
#define MFMA16(a,b,c) __builtin_amdgcn_mfma_f32_16x16x32_bf16(a,b,c,0,0,0)

// Merged setup: blocks [0,2048) prep; [2048,14336) weight transpose; [14336,14592) uv.
__global__ __launch_bounds__(256) void setup_kernel(
    const float* __restrict__ x, const float* __restrict__ pos,
    u16* __restrict__ h, float2* __restrict__ pstat, u16* __restrict__ qkv,
    const float* __restrict__ wq, const float* __restrict__ wk,
    const float* __restrict__ wv, const float* __restrict__ wo,
    const float* __restrict__ w1, const float* __restrict__ w2,
    const float* __restrict__ ln1s, const float* __restrict__ ln1b,
    const float* __restrict__ ln2s, const float* __restrict__ ln2b,
    u16* __restrict__ wT, float* __restrict__ uvbuf)
{
  __shared__ __align__(16) float smem[6336];
  int bid = blockIdx.x;
  int tid = threadIdx.x;
  if(bid < 2048){
    float* t = smem;   // [49*129]
    int b = bid >> 3, yy = bid & 7, c0 = yy*128;
    int lane = tid & 63, wave = tid >> 6;
    if(b == 0){
      uint4* pz = (uint4*)(qkv + (size_t)Mq*STq + (size_t)yy*6144);
      pz[tid] = make_uint4(0,0,0,0);
      pz[256+tid] = make_uint4(0,0,0,0);
      pz[512+tid] = make_uint4(0,0,0,0);
    }
    const float* xb = x + (size_t)b*(Dq*Sq) + (size_t)c0*Sq;
    #pragma unroll
    for(int i=0;i<32;i++){
      int cc = wave + i*4;
      if(lane < Sq) t[lane*129 + cc] = xb[(size_t)cc*Sq + lane];
    }
    __syncthreads();
    #pragma unroll
    for(int p=0;p<25;p++){
      int idx = p*256 + tid;
      int s = idx >> 7, cc = idx & 127;
      if(s < Sq){
        float hv = t[s*129 + cc] + pos[s*Dq + c0 + cc];
        h[((size_t)b*Sq + s)*Dq + c0 + cc] = f2bf(hv);
        t[s*129 + cc] = hv;
      }
    }
    __syncthreads();
    int r = tid >> 2, qd = tid & 3;
    if(r < Sq){
      float S=0.f, Q=0.f;
      for(int cc=qd; cc<128; cc+=4){ float vv = t[r*129+cc]; S+=vv; Q+=vv*vv; }
      S += __shfl_xor(S,1); Q += __shfl_xor(Q,1);
      S += __shfl_xor(S,2); Q += __shfl_xor(Q,2);
      if(qd==0){ float2 pp; pp.x=S; pp.y=Q; pstat[(size_t)yy*Mq + b*Sq + r] = pp; }
    }
  } else if(bid < 14336){
    int j = bid - 2048;
    int slot = j >> 10, jb = j & 1023;
    int k0 = (jb & 31)*32, n0 = (jb >> 5)*32;
    int l = slot / 6, jj = slot - l*6;
    const float* srcs[6] = {wq,wk,wv,wo,w1,w2};
    const float* in = srcs[jj] + (size_t)l*Dq*Dq;
    const float* sc = (jj<3) ? (ln1s + l*Dq) : (jj==4 ? (ln2s + l*Dq) : nullptr);
    u16* o = wT + (size_t)slot*Dq*Dq;
    float (*t)[33] = (float(*)[33])smem;
    int tx = tid & 31, ty = tid >> 5;
    #pragma unroll
    for(int i=0;i<4;i++) t[ty+8*i][tx] = in[(size_t)(k0+ty+8*i)*Dq + n0+tx];
    __syncthreads();
    float sck = sc ? sc[k0+tx] : 1.f;
    #pragma unroll
    for(int i=0;i<4;i++) o[(size_t)(n0+ty+8*i)*Dq + k0+tx] = f2bf(t[tx][ty+8*i] * sck);
  } else {
    int j = bid - 14336;
    float2 (*red)[32] = (float2(*)[32])smem;
    int t = tid;
    int colg = j*32 + (t & 31);
    int ks = t >> 5;
    int l = colg >> 12, col = colg & 4095;
    int jj = col >> 10, n = col & 1023;
    const float* srcs[4] = {wq, wk, wv, w1};
    const float* src = srcs[jj] + (size_t)l*Dq*Dq;
    const float* sc = (jj<3 ? ln1s : ln2s) + l*Dq;
    const float* bi = (jj<3 ? ln1b : ln2b) + l*Dq;
    float u=0.f, v=0.f;
    for(int k=ks*128;k<ks*128+128;k++){
      float val = src[(size_t)k*Dq + n];
      u += sc[k]*val; v += bi[k]*val;
    }
    float2 pp; pp.x=u; pp.y=v;
    red[ks][t&31] = pp;
    __syncthreads();
    if(t < 32){
      float U=0.f, V=0.f;
      #pragma unroll
      for(int s2=0;s2<8;s2++){ float2 q2 = red[s2][t]; U+=q2.x; V+=q2.y; }
      uvbuf[(size_t)(j*32 + t)*2]   = U;
      uvbuf[(size_t)(j*32 + t)*2+1] = V;
    }
  }
}

// LayerNorm over D=1024 (only lnf before the head)
__global__ __launch_bounds__(256) void ln_kernel(const u16* __restrict__ hin,
    const float* __restrict__ sc, const float* __restrict__ bi, u16* __restrict__ outp){
  int wave = threadIdx.x >> 6, lane = threadIdx.x & 63;
  int row = blockIdx.x*4 + wave;
  const u16* p = hin + (size_t)row*Dq + lane*16;
  uint4 t0 = *(const uint4*)p;
  uint4 t1 = *(const uint4*)(p + 8);
  float v[16];
  {
    uint32_t wds[8] = {t0.x,t0.y,t0.z,t0.w,t1.x,t1.y,t1.z,t1.w};
    #pragma unroll
    for(int i=0;i<8;i++){
      v[2*i]   = bf2f((u16)(wds[i] & 0xffff));
      v[2*i+1] = bf2f((u16)(wds[i] >> 16));
    }
  }
  float s=0.f, sq=0.f;
  #pragma unroll
  for(int i=0;i<16;i++){ s += v[i]; sq += v[i]*v[i]; }
  #pragma unroll
  for(int o=32;o>=1;o>>=1){ s += __shfl_xor(s,o); sq += __shfl_xor(sq,o); }
  float mean = s * (1.f/Dq);
  float var  = sq * (1.f/Dq) - mean*mean;
  float rs = rsqrtf(var + 1e-5f);
  int c0 = lane*16;
  uint32_t w[8];
  #pragma unroll
  for(int i=0;i<8;i++){
    u16 lo = f2bf((v[2*i]   - mean)*rs*sc[c0+2*i]   + bi[c0+2*i]);
    u16 hi = f2bf((v[2*i+1] - mean)*rs*sc[c0+2*i+1] + bi[c0+2*i+1]);
    w[i] = (uint32_t)lo | ((uint32_t)hi << 16);
  }
  uint4* ob = (uint4*)(outp + (size_t)row*Dq + c0);
  ob[0] = make_uint4(w[0],w[1],w[2],w[3]);
  ob[1] = make_uint4(w[4],w[5],w[6],w[7]);
}

// ================= 256x256 8-wave 4-phase NT GEMM (K=1024), persistent tiles ====
// m201-style uniform phases: P0 = 12 ds_read (all B + A0/A1) + 16 MFMA; P1-P3 =
// 4 ds_read + 16 MFMA. 8 barriers/tile (was 10). Stage h0@P0, h1+h2@P1, h3@P2;
// boundary vmcnt(2) unchanged.
// EPI 0: qkv (consume LN stats)  EPI 1: resid-add (produce)  EPI 2: gelu-w1 (consume)
template<int EPI>
__global__ __launch_bounds__(512, 2) void gemm_nt2(
    const u16* __restrict__ A, int lda,
    const u16* __restrict__ Bt, int ldb,
    void* __restrict__ Cout, const u16* __restrict__ resid,
    const float* __restrict__ bias, int ldc,
    const float2* __restrict__ pstat_in, int nchunk,
    const float* __restrict__ uvp, float2* __restrict__ pstat_out,
    int total, int gxT)
{
  __shared__ u16 lds[65536];
  int tid = threadIdx.x, lane = tid & 63;
  int wave = tid >> 6;
  int wm = wave >> 2, wn = wave & 3;
  int l15 = lane & 15, l4 = lane >> 4;
  int swz = (l15 & 7) << 4;

  int srow = tid >> 3, scolb = (tid & 7) * 16;
  int scolx = scolb ^ ((srow & 7) << 4);

  for(int w = blockIdx.x; w < total; w += gridDim.x){
    int qq = total >> 3, rr = total & 7;
    int xcd = w & 7, idx = w >> 3;
    int wgid = (xcd < rr ? xcd*(qq+1) : rr*(qq+1) + (xcd-rr)*qq) + idx;
    int bx = wgid % gxT, by = wgid / gxT;
    int m0 = by*256, n0 = bx*256;

    auto stage2 = [&](int d, int kt, int h){
      #pragma unroll
      for(int cc=0; cc<2; cc++){
        int c = 2*h + cc;
        if(c < 4){
          int row = c*64 + srow;
          const u16* src = A + (size_t)(m0+row)*lda + kt*64 + (scolx>>1);
          GLOAD_LDS16(src, &lds[d*16384 + c*4096 + tid*8]);
        } else {
          int c4 = c - 4;
          int row = c4*64 + srow;
          const u16* src = Bt + (size_t)(n0+row)*ldb + kt*64 + (scolx>>1);
          GLOAD_LDS16(src, &lds[32768 + d*16384 + c4*4096 + tid*8]);
        }
      }
    };
    auto rdA = [&](int d, int i, int s)->bf16x8{
      int row = wm*128 + i*16 + l15;
      int byt = row*128 + ((s*64 + l4*16) ^ swz);
      return *(const bf16x8*)((const char*)lds + d*32768 + byt);
    };
    auto rdB = [&](int d, int n, int s)->bf16x8{
      int row = wn*64 + n*16 + l15;
      int byt = row*128 + ((s*64 + l4*16) ^ swz);
      return *(const bf16x8*)((const char*)lds + 65536 + d*32768 + byt);
    };

    f32x4 acc[8][4] = {};

    // barrier so prior tile's epilogue LDS reads are complete before restaging
    __syncthreads();
    #pragma unroll
    for(int h=0;h<4;h++) stage2(0, 0, h);

    for(int t=0; t<16; ++t){
      int d = t & 1;
      bf16x8 bfr[4][2];
      // ---- P0: boundary wait; all B frags + A0/A1; 16 MFMA (acc[0],acc[1]) ----
      if(t < 15){
        stage2(d^1, t+1, 0);
        asm volatile("s_waitcnt vmcnt(2)" ::: "memory");
      } else {
        asm volatile("s_waitcnt vmcnt(0)" ::: "memory");
      }
      __builtin_amdgcn_sched_barrier(0);
      __builtin_amdgcn_s_barrier();
      #pragma unroll
      for(int n=0;n<4;n++){ bfr[n][0]=rdB(d,n,0); bfr[n][1]=rdB(d,n,1); }
      bf16x8 a0s0=rdA(d,0,0), a0s1=rdA(d,0,1), a1s0=rdA(d,1,0), a1s1=rdA(d,1,1);
      __builtin_amdgcn_s_setprio(1);
      #pragma unroll
      for(int n=0;n<4;n++){
        acc[0][n]=MFMA16(a0s0,bfr[n][0],acc[0][n]); acc[0][n]=MFMA16(a0s1,bfr[n][1],acc[0][n]);
        acc[1][n]=MFMA16(a1s0,bfr[n][0],acc[1][n]); acc[1][n]=MFMA16(a1s1,bfr[n][1],acc[1][n]);
      }
      __builtin_amdgcn_s_setprio(0);
      __builtin_amdgcn_s_barrier();
      // ---- P1..P3 (q=1..3): A quads; stage h1+h2 at q=1, h3 at q=2 ----
      #pragma unroll
      for(int q=1;q<4;q++){
        bf16x8 c0s0=rdA(d,2*q,0), c0s1=rdA(d,2*q,1), c1s0=rdA(d,2*q+1,0), c1s1=rdA(d,2*q+1,1);
        if(t < 15){
          if(q == 1){ stage2(d^1, t+1, 1); stage2(d^1, t+1, 2); }
          if(q == 2){ stage2(d^1, t+1, 3); }
        }
        __builtin_amdgcn_s_barrier();
        __builtin_amdgcn_s_setprio(1);
        #pragma unroll
        for(int n=0;n<4;n++){
          acc[2*q][n]   = MFMA16(c0s0, bfr[n][0], acc[2*q][n]);
          acc[2*q][n]   = MFMA16(c0s1, bfr[n][1], acc[2*q][n]);
          acc[2*q+1][n] = MFMA16(c1s0, bfr[n][0], acc[2*q+1][n]);
          acc[2*q+1][n] = MFMA16(c1s1, bfr[n][1], acc[2*q+1][n]);
        }
        __builtin_amdgcn_s_setprio(0);
        __builtin_amdgcn_s_barrier();
      }
    }

    // ---- epilogue ----
    if constexpr (EPI == 1){
      float2* statsS = (float2*)((char*)lds + 49152);
      float* slotf = (float*)((char*)lds + wave*4096);
      float bv[4];
      #pragma unroll
      for(int n=0;n<4;n++) bv[n] = bias ? bias[n0 + wn*64 + n*16 + l15] : 0.f;
      #pragma unroll
      for(int i=0;i<8;i++){
        #pragma unroll
        for(int n=0;n<4;n++)
          #pragma unroll
          for(int r=0;r<4;r++)
            slotf[(l4*4+r)*64 + n*16 + l15] = acc[i][n][r] + bv[n];
        #pragma unroll
        for(int st=0;st<2;st++){
          int u = st*64 + lane;
          int row = u >> 3, c8 = (u & 7)*8;
          f32x4 lo = *(const f32x4*)&slotf[row*64 + c8];
          f32x4 hi = *(const f32x4*)&slotf[row*64 + c8 + 4];
          size_t o = (size_t)(m0 + wm*128 + i*16 + row)*ldc + n0 + wn*64 + c8;
          bf16x8 rb = *(const bf16x8*)(resid + o);
          bf16x8 ov; float fs=0.f, fq=0.f;
          #pragma unroll
          for(int j=0;j<4;j++){
            float a_ = lo[j] + bf2f((u16)rb[j]);
            float b_ = hi[j] + bf2f((u16)rb[4+j]);
            ov[j]   = (short)f2bf(a_);
            ov[4+j] = (short)f2bf(b_);
            fs += a_ + b_; fq += a_*a_ + b_*b_;
          }
          *(bf16x8*)((u16*)Cout + o) = ov;
          fs += __shfl_xor(fs,1); fq += __shfl_xor(fq,1);
          fs += __shfl_xor(fs,2); fq += __shfl_xor(fq,2);
          fs += __shfl_xor(fs,4); fq += __shfl_xor(fq,4);
          if((lane&7)==0){
            float2 pp; pp.x=fs; pp.y=fq;
            statsS[(wm*128 + i*16 + st*8 + (lane>>3))*4 + wn] = pp;
          }
        }
      }
      __syncthreads();
      if(tid < 256){
        float S=0.f, Q=0.f;
        #pragma unroll
        for(int w2_=0;w2_<4;w2_++){ float2 pp = statsS[tid*4+w2_]; S+=pp.x; Q+=pp.y; }
        float2 pp; pp.x=S; pp.y=Q;
        pstat_out[(size_t)bx*Mq + m0 + tid] = pp;
      }
    } else {
      float2* lstat = (float2*)((char*)lds + 49152);
      if(tid < 256){
        float S=0.f, Q=0.f;
        for(int c=0;c<nchunk;c++){ float2 pp = pstat_in[(size_t)c*Mq + m0 + tid]; S+=pp.x; Q+=pp.y; }
        float mean = S*(1.f/1024.f);
        float var  = Q*(1.f/1024.f) - mean*mean;
        float2 sm; sm.x = rsqrtf(var + 1e-5f); sm.y = mean;
        lstat[tid] = sm;
      }
      __syncthreads();
      u16* slot = (u16*)((char*)lds + wave*2048);
      float uvv[4][2], bv[4];
      #pragma unroll
      for(int n=0;n<4;n++){
        int ncol = n0 + wn*64 + n*16 + l15;
        float2 uv2 = ((const float2*)uvp)[ncol];
        uvv[n][0] = uv2.x; uvv[n][1] = uv2.y;
        if constexpr (EPI == 2) bv[n] = bias[ncol];
      }
      #pragma unroll
      for(int i=0;i<8;i++){
        #pragma unroll
        for(int n=0;n<4;n++)
          #pragma unroll
          for(int r=0;r<4;r++){
            float2 sm = lstat[wm*128 + i*16 + l4*4 + r];
            float va = sm.x*acc[i][n][r] - sm.x*sm.y*uvv[n][0] + uvv[n][1];
            u16 ov;
            if constexpr (EPI == 0){
              ov = f2bf(va);
            } else {
              float xg = va + bv[n];
              float tg = tanhf(0.79788456080286536f*(xg + 0.044715f*xg*xg*xg));
              ov = f2bf(0.5f*xg*(1.f+tg));
            }
            slot[(l4*4+r)*64 + n*16 + l15] = ov;
          }
        #pragma unroll
        for(int st=0;st<2;st++){
          int u = st*64 + lane;
          int row = u >> 3, c8 = (u & 7)*8;
          bf16x8 v8 = *(const bf16x8*)&slot[row*64 + c8];
          *(bf16x8*)((u16*)Cout + (size_t)(m0 + wm*128 + i*16 + row)*ldc + n0 + wn*64 + c8) = v8;
        }
      }
    }
  }
}

// Head GEMM v3: M=128 tile, grid (8,2,49)=784 blocks (~3/CU), software-pipelined.
__global__ __launch_bounds__(256, 3) void gemm_head(
    const u16* __restrict__ A, const float* __restrict__ W,
    u16* __restrict__ parts)
{
  __shared__ u16 sA[2][128*32];   // 2 x 8 KB double-buffered A tiles
  int tid = threadIdx.x, lane = tid & 63;
  int wave = tid >> 6;
  int wm = wave >> 1, wn = wave & 1;
  int l15 = lane & 15, l4 = lane >> 4;
  int bx = blockIdx.x, by = blockIdx.y, z = blockIdx.z;
  int n0 = bx*128, m0 = by*128;
  size_t abase = (size_t)m0*KHEADq + (size_t)z*1024;
  f32x4 acc[4][4] = {};
  const float* wp = W + ((size_t)z*1024 + (size_t)l4*8)*1024 + n0 + wn*64 + l15;

  auto stageA = [&](int d, int kt){
    #pragma unroll
    for(int c=0;c<2;c++){
      int s2 = c*256+tid;
      GLOAD_LDS16(A + abase + (size_t)(s2>>2)*KHEADq + kt*32 + (s2&3)*8, &sA[d][s2*8]);
    }
  };
  float wA[4][8], wB[4][8];
  auto loadW = [&](float (&dst)[4][8], int kt){
    #pragma unroll
    for(int f=0;f<4;f++)
      #pragma unroll
      for(int jj=0;jj<8;jj++)
        dst[f][jj] = wp[(size_t)(kt*32+jj)*1024 + f*16];
  };
  auto compute = [&](int d, float (&wreg)[4][8]){
    bf16x8 bfr[4];
    #pragma unroll
    for(int f=0;f<4;f++){
      bf16x8 bv;
      #pragma unroll
      for(int jj=0;jj<8;jj++)
        bv[jj] = __builtin_bit_cast(short, __float2bfloat16(wreg[f][jj]));
      bfr[f] = bv;
    }
    bf16x8 af[4];
    #pragma unroll
    for(int i=0;i<4;i++)
      af[i] = *(const bf16x8*)&sA[d][(wm*64 + i*16 + l15)*32 + l4*8];
    #pragma unroll
    for(int i=0;i<4;i++)
      #pragma unroll
      for(int j=0;j<4;j++)
        acc[i][j] = MFMA16(af[i], bfr[j], acc[i][j]);
  };

  stageA(0, 0);
  loadW(wA, 0);
  for(int k2=0; k2<16; ++k2){
    int kt = 2*k2;
    stageA(1, kt+1);
    loadW(wB, kt+1);
    asm volatile("s_waitcnt vmcnt(34)" ::: "memory");
    __builtin_amdgcn_s_barrier();
    compute(0, wA);
    __builtin_amdgcn_s_barrier();
    if(k2 < 15){
      stageA(0, kt+2);
      loadW(wA, kt+2);
      asm volatile("s_waitcnt vmcnt(34)" ::: "memory");
    } else {
      asm volatile("s_waitcnt vmcnt(0)" ::: "memory");
    }
    __builtin_amdgcn_s_barrier();
    compute(1, wB);
    __builtin_amdgcn_s_barrier();
  }

  u16* slot = &sA[0][wave*1024];
  u16* base = parts + (size_t)z*(Bq*1024);
  #pragma unroll
  for(int i=0;i<4;i++){
    #pragma unroll
    for(int j=0;j<4;j++)
      #pragma unroll
      for(int rr=0;rr<4;rr++)
        slot[(l4*4+rr)*64 + j*16 + l15] = f2bf(acc[i][j][rr]);
    #pragma unroll
    for(int st=0;st<2;st++){
      int u = st*64 + lane;
      int row = u >> 3, c8 = (u & 7)*8;
      bf16x8 v8 = *(const bf16x8*)&slot[row*64 + c8];
      *(bf16x8*)(base + (size_t)(m0 + wm*64 + i*16 + row)*1024 + n0 + wn*64 + c8) = v8;
    }
  }
}

// Fused attention per (b,h); wave-parallel softmax; V staged in LDS (two halves).
__global__ __launch_bounds__(256) void attn_kernel(u16* __restrict__ qkv)
{
  __shared__ float sS[64][65];
  __shared__ u16 sP[64][64];
  __shared__ __align__(16) u16 sV[64*260 + 4];
  int bh = blockIdx.x;
  int b = bh >> 1, h = bh & 1;
  int tid = threadIdx.x, lane = tid & 63, wave = tid >> 6;
  int l15 = lane & 15, l4 = lane >> 4;
  f32x4 zero4 = {0.f,0.f,0.f,0.f};
  bf16x8 zb = {0,0,0,0,0,0,0,0};
  f32x4 acc[4];
  #pragma unroll
  for(int i=0;i<4;i++) acc[i] = zero4;
  int srow = wave*16 + l15;
  const u16* qp = qkv + (size_t)(b*Sq + srow)*STq + h*HDq + l4*8;
  const u16* kbase = qkv + (size_t)b*Sq*STq + Dq + h*HDq + l4*8;
  for(int kt=0;kt<16;kt++){
    bf16x8 aq = (srow < Sq) ? *(const bf16x8*)(qp + kt*32) : zb;
    #pragma unroll
    for(int fn=0;fn<4;fn++){
      int s2 = fn*16 + l15;
      bf16x8 bk = (s2 < Sq) ? *(const bf16x8*)(kbase + (size_t)s2*STq + kt*32) : zb;
      acc[fn] = MFMA16(aq, bk, acc[fn]);
    }
  }
  const float scale = 0.04419417382415922f; // 1/sqrt(512)
  #pragma unroll
  for(int fn=0;fn<4;fn++)
    #pragma unroll
    for(int r=0;r<4;r++)
      sS[wave*16 + l4*4 + r][fn*16 + l15] = acc[fn][r]*scale;
  const u16* vsrc = qkv + (size_t)b*Sq*STq + 2*Dq + h*HDq;
  #pragma unroll
  for(int p=0;p<16;p++){
    int i = p*256 + tid;
    int row = i >> 6, ch = i & 63;
    uint2 v2 = (row < Sq) ? *(const uint2*)(vsrc + (size_t)row*STq + ch*4) : make_uint2(0u,0u);
    *(uint2*)&sV[row*260 + ch*4] = v2;
  }
  __syncthreads();
  {
    int r = tid >> 2, qd = tid & 3;
    float mx = -1e30f;
    for(int j=qd;j<Sq;j+=4) mx = fmaxf(mx, sS[r][j]);
    mx = fmaxf(mx, __shfl_xor(mx,1));
    mx = fmaxf(mx, __shfl_xor(mx,2));
    float sum = 0.f;
    for(int j=qd;j<Sq;j+=4){ float e = __expf(sS[r][j]-mx); sS[r][j]=e; sum+=e; }
    sum += __shfl_xor(sum,1);
    sum += __shfl_xor(sum,2);
    float inv = 1.f/sum;
    for(int j=qd;j<64;j+=4) sP[r][j] = (j<Sq)? f2bf(sS[r][j]*inv) : (u16)0;
  }
  uint2 vreg[16];
  #pragma unroll
  for(int p=0;p<16;p++){
    int i = p*256 + tid;
    int row = i >> 6, ch = i & 63;
    vreg[p] = (row < Sq) ? *(const uint2*)(vsrc + 256 + (size_t)row*STq + ch*4) : make_uint2(0u,0u);
  }
  __syncthreads();
  bf16x8 ap[2];
  #pragma unroll
  for(int kt2=0;kt2<2;kt2++)
    ap[kt2] = *(const bf16x8*)&sP[wave*16 + l15][kt2*32 + l4*8];
  u16* cb = qkv + (size_t)b*Sq*STq + h*HDq;
  for(int fn=0;fn<16;fn++){
    f32x4 c4 = zero4;
    #pragma unroll
    for(int kt2=0;kt2<2;kt2++){
      int rbase = kt2*32 + l4*8;
      bf16x8 bv;
      #pragma unroll
      for(int jj=0;jj<8;jj++) bv[jj] = (short)sV[(rbase+jj)*260 + fn*16 + l15];
      c4 = MFMA16(ap[kt2], bv, c4);
    }
    #pragma unroll
    for(int r=0;r<4;r++){
      int s = wave*16 + l4*4 + r;
      if(s < Sq) cb[(size_t)s*STq + fn*16 + l15] = f2bf(c4[r]);
    }
  }
  __syncthreads();
  #pragma unroll
  for(int p=0;p<16;p++){
    int i = p*256 + tid;
    int row = i >> 6, ch = i & 63;
    *(uint2*)&sV[row*260 + ch*4] = vreg[p];
  }
  __syncthreads();
  for(int fn=16;fn<32;fn++){
    f32x4 c4 = zero4;
    #pragma unroll
    for(int kt2=0;kt2<2;kt2++){
      int rbase = kt2*32 + l4*8;
      bf16x8 bv;
      #pragma unroll
      for(int jj=0;jj<8;jj++) bv[jj] = (short)sV[(rbase+jj)*260 + (fn-16)*16 + l15];
      c4 = MFMA16(ap[kt2], bv, c4);
    }
    #pragma unroll
    for(int r=0;r<4;r++){
      int s = wave*16 + l4*4 + r;
      if(s < Sq) cb[(size_t)s*STq + fn*16 + l15] = f2bf(c4[r]);
    }
  }
}

__global__ __launch_bounds__(256) void head_finalize(const u16* __restrict__ parts,
    const float* __restrict__ hb, float* __restrict__ outp){
  int idx = blockIdx.x*256 + threadIdx.x;
  float s = hb[idx & 1023];
  #pragma unroll
  for(int z=0;z<49;z++) s += bf2f(parts[(size_t)z*(Bq*1024) + idx]);
  outp[idx] = fmaxf(s, 0.f);
}

extern "C" void kernel_launch(void* const* d_in, const int* in_sizes, int n_in,
                              void* d_out, int out_size, void* d_ws, size_t ws_size,
                              hipStream_t stream) {
  (void)in_sizes; (void)n_in; (void)out_size;
  const float* x    = (const float*)d_in[0];
  const float* pos  = (const float*)d_in[1];
  const float* ln1s = (const float*)d_in[2];
  const float* ln1b = (const float*)d_in[3];
  const float* wq   = (const float*)d_in[4];
  const float* wk   = (const float*)d_in[5];
  const float* wv   = (const float*)d_in[6];
  const float* wo   = (const float*)d_in[7];
  const float* ln2s = (const float*)d_in[8];
  const float* ln2b = (const float*)d_in[9];
  const float* w1   = (const float*)d_in[10];
  const float* b1   = (const float*)d_in[11];
  const float* w2   = (const float*)d_in[12];
  const float* b2   = (const float*)d_in[13];
  const float* lnfs = (const float*)d_in[14];
  const float* lnfb = (const float*)d_in[15];
  const float* hw   = (const float*)d_in[16];
  const float* hb   = (const float*)d_in[17];
  float* out = (float*)d_out;

  char* ws = (char*)d_ws;
  size_t off = 0;
  auto carve = [&](size_t n) -> char* { char* p = ws + off; off += (n + 255) & ~(size_t)255; return p; };
  u16*   h     = (u16*)  carve((size_t)Mq*Dq*2);
  u16*   act0  = (u16*)  carve((size_t)Mq*Dq*2);
  u16*   act1  = (u16*)  carve((size_t)Mq*Dq*2);
  u16*   qkv   = (u16*)  carve((size_t)(Mq+16)*STq*2);
  u16*   wT    = (u16*)  carve((size_t)12*Dq*Dq*2);
  float2* pstat= (float2*)carve((size_t)8*Mq*sizeof(float2));
  float* uvbuf = (float*)carve((size_t)2*4096*2*4);
  u16*   parts = qkv;   // head partials (bf16, 25.7 MB) alias qkv (dead by head time)
  if (off > ws_size) return;

  setup_kernel<<<14592, 256, 0, stream>>>(x, pos, h, pstat, qkv,
      wq, wk, wv, wo, w1, w2, ln1s, ln1b, ln2s, ln2b, wT, uvbuf);

  for(int l=0;l<2;l++){
    u16* qkvT = wT + (size_t)(l*6+0)*Dq*Dq;
    u16* woT  = wT + (size_t)(l*6+3)*Dq*Dq;
    u16* w1T  = wT + (size_t)(l*6+4)*Dq*Dq;
    u16* w2T  = wT + (size_t)(l*6+5)*Dq*Dq;
    const float* uvq = uvbuf + (size_t)l*8192;
    const float* uv1 = uvbuf + (size_t)l*8192 + 3072*2;

    gemm_nt2<0><<<512, 512, 0, stream>>>(h, Dq, qkvT, Dq, qkv, nullptr, nullptr, STq,
                                         pstat, (l==0)?8:4, uvq, nullptr, 588, 12);
    attn_kernel<<<Bq*Hq, 256, 0, stream>>>(qkv);
    gemm_nt2<1><<<196, 512, 0, stream>>>(qkv, STq, woT, Dq, h, h, nullptr, Dq,
                                         nullptr, 0, nullptr, pstat, 196, 4);
    gemm_nt2<2><<<196, 512, 0, stream>>>(h, Dq, w1T, Dq, act1, nullptr, b1 + l*Dq, Dq,
                                         pstat, 4, uv1, nullptr, 196, 4);
    gemm_nt2<1><<<196, 512, 0, stream>>>(act1, Dq, w2T, Dq, h, h, b2 + l*Dq, Dq,
                                         nullptr, 0, nullptr, pstat, 196, 4);
  }

  ln_kernel<<<Mq/4, 256, 0, stream>>>(h, lnfs, lnfb, act0);
  gemm_head<<<dim3(8,2,49), 256, 0, stream>>>(act0, hw, parts);
  head_finalize<<<1024, 256, 0, stream>>>(parts, hb, out);
}

// Round 18
// 670.543 us; speedup vs baseline: 1.0217x; 1.0217x over previous
//
#include <hip/hip_runtime.h>
#include <hip/hip_bf16.h>
#include <stdint.h>

#define Bq 256
#define Sq 49
#define Dq 1024
#define Hq 2
#define HDq 512
#define Mq (Bq*Sq)        // 12544
#define KHEADq (Sq*Dq)    // 50176
#define STq 3072          // fused qkv row stride

typedef unsigned short u16;
typedef short bf16x8 __attribute__((ext_vector_type(8)));
typedef float f32x4 __attribute__((ext_vector_type(4)));

__device__ inline u16 f2bf(float f){
  union { float f; uint32_t u; } c; c.f = f;
  uint32_t r = c.u + 0x7FFFu + ((c.u >> 16) & 1u);
  return (u16)(r >> 16);
}
__device__ inline float bf2f(u16 h){
  union { uint32_t u; float f; } c; c.u = ((uint32_t)h) << 16;
  return c.f;
}

#define GLOAD_LDS16(gp, lp) \
  __builtin_amdgcn_global_load_lds((__attribute__((address_space(1))) void*)(gp), \
                                   (__attribute__((address_space(3))) void*)(lp), 16, 0, 0)
#define MFMA16(a,b,c) __builtin_amdgcn_mfma_f32_16x16x32_bf16(a,b,c,0,0,0)

// Merged setup: blocks [0,2048) prep; [2048,14336) weight transpose; [14336,14592) uv.
__global__ __launch_bounds__(256) void setup_kernel(
    const float* __restrict__ x, const float* __restrict__ pos,
    u16* __restrict__ h, float2* __restrict__ pstat, u16* __restrict__ qkv,
    const float* __restrict__ wq, const float* __restrict__ wk,
    const float* __restrict__ wv, const float* __restrict__ wo,
    const float* __restrict__ w1, const float* __restrict__ w2,
    const float* __restrict__ ln1s, const float* __restrict__ ln1b,
    const float* __restrict__ ln2s, const float* __restrict__ ln2b,
    u16* __restrict__ wT, float* __restrict__ uvbuf)
{
  __shared__ __align__(16) float smem[6336];
  int bid = blockIdx.x;
  int tid = threadIdx.x;
  if(bid < 2048){
    float* t = smem;   // [49*129]
    int b = bid >> 3, yy = bid & 7, c0 = yy*128;
    int lane = tid & 63, wave = tid >> 6;
    if(b == 0){
      uint4* pz = (uint4*)(qkv + (size_t)Mq*STq + (size_t)yy*6144);
      pz[tid] = make_uint4(0,0,0,0);
      pz[256+tid] = make_uint4(0,0,0,0);
      pz[512+tid] = make_uint4(0,0,0,0);
    }
    const float* xb = x + (size_t)b*(Dq*Sq) + (size_t)c0*Sq;
    #pragma unroll
    for(int i=0;i<32;i++){
      int cc = wave + i*4;
      if(lane < Sq) t[lane*129 + cc] = xb[(size_t)cc*Sq + lane];
    }
    __syncthreads();
    #pragma unroll
    for(int p=0;p<25;p++){
      int idx = p*256 + tid;
      int s = idx >> 7, cc = idx & 127;
      if(s < Sq){
        float hv = t[s*129 + cc] + pos[s*Dq + c0 + cc];
        h[((size_t)b*Sq + s)*Dq + c0 + cc] = f2bf(hv);
        t[s*129 + cc] = hv;
      }
    }
    __syncthreads();
    int r = tid >> 2, qd = tid & 3;
    if(r < Sq){
      float S=0.f, Q=0.f;
      for(int cc=qd; cc<128; cc+=4){ float vv = t[r*129+cc]; S+=vv; Q+=vv*vv; }
      S += __shfl_xor(S,1); Q += __shfl_xor(Q,1);
      S += __shfl_xor(S,2); Q += __shfl_xor(Q,2);
      if(qd==0){ float2 pp; pp.x=S; pp.y=Q; pstat[(size_t)yy*Mq + b*Sq + r] = pp; }
    }
  } else if(bid < 14336){
    int j = bid - 2048;
    int slot = j >> 10, jb = j & 1023;
    int k0 = (jb & 31)*32, n0 = (jb >> 5)*32;
    int l = slot / 6, jj = slot - l*6;
    const float* srcs[6] = {wq,wk,wv,wo,w1,w2};
    const float* in = srcs[jj] + (size_t)l*Dq*Dq;
    const float* sc = (jj<3) ? (ln1s + l*Dq) : (jj==4 ? (ln2s + l*Dq) : nullptr);
    u16* o = wT + (size_t)slot*Dq*Dq;
    float (*t)[33] = (float(*)[33])smem;
    int tx = tid & 31, ty = tid >> 5;
    #pragma unroll
    for(int i=0;i<4;i++) t[ty+8*i][tx] = in[(size_t)(k0+ty+8*i)*Dq + n0+tx];
    __syncthreads();
    float sck = sc ? sc[k0+tx] : 1.f;
    #pragma unroll
    for(int i=0;i<4;i++) o[(size_t)(n0+ty+8*i)*Dq + k0+tx] = f2bf(t[tx][ty+8*i] * sck);
  } else {
    int j = bid - 14336;
    float2 (*red)[32] = (float2(*)[32])smem;
    int t = tid;
    int colg = j*32 + (t & 31);
    int ks = t >> 5;
    int l = colg >> 12, col = colg & 4095;
    int jj = col >> 10, n = col & 1023;
    const float* srcs[4] = {wq, wk, wv, w1};
    const float* src = srcs[jj] + (size_t)l*Dq*Dq;
    const float* sc = (jj<3 ? ln1s : ln2s) + l*Dq;
    const float* bi = (jj<3 ? ln1b : ln2b) + l*Dq;
    float u=0.f, v=0.f;
    for(int k=ks*128;k<ks*128+128;k++){
      float val = src[(size_t)k*Dq + n];
      u += sc[k]*val; v += bi[k]*val;
    }
    float2 pp; pp.x=u; pp.y=v;
    red[ks][t&31] = pp;
    __syncthreads();
    if(t < 32){
      float U=0.f, V=0.f;
      #pragma unroll
      for(int s2=0;s2<8;s2++){ float2 q2 = red[s2][t]; U+=q2.x; V+=q2.y; }
      uvbuf[(size_t)(j*32 + t)*2]   = U;
      uvbuf[(size_t)(j*32 + t)*2+1] = V;
    }
  }
}

// LayerNorm over D=1024 (only lnf before the head)
__global__ __launch_bounds__(256) void ln_kernel(const u16* __restrict__ hin,
    const float* __restrict__ sc, const float* __restrict__ bi, u16* __restrict__ outp){
  int wave = threadIdx.x >> 6, lane = threadIdx.x & 63;
  int row = blockIdx.x*4 + wave;
  const u16* p = hin + (size_t)row*Dq + lane*16;
  uint4 t0 = *(const uint4*)p;
  uint4 t1 = *(const uint4*)(p + 8);
  float v[16];
  {
    uint32_t wds[8] = {t0.x,t0.y,t0.z,t0.w,t1.x,t1.y,t1.z,t1.w};
    #pragma unroll
    for(int i=0;i<8;i++){
      v[2*i]   = bf2f((u16)(wds[i] & 0xffff));
      v[2*i+1] = bf2f((u16)(wds[i] >> 16));
    }
  }
  float s=0.f, sq=0.f;
  #pragma unroll
  for(int i=0;i<16;i++){ s += v[i]; sq += v[i]*v[i]; }
  #pragma unroll
  for(int o=32;o>=1;o>>=1){ s += __shfl_xor(s,o); sq += __shfl_xor(sq,o); }
  float mean = s * (1.f/Dq);
  float var  = sq * (1.f/Dq) - mean*mean;
  float rs = rsqrtf(var + 1e-5f);
  int c0 = lane*16;
  uint32_t w[8];
  #pragma unroll
  for(int i=0;i<8;i++){
    u16 lo = f2bf((v[2*i]   - mean)*rs*sc[c0+2*i]   + bi[c0+2*i]);
    u16 hi = f2bf((v[2*i+1] - mean)*rs*sc[c0+2*i+1] + bi[c0+2*i+1]);
    w[i] = (uint32_t)lo | ((uint32_t)hi << 16);
  }
  uint4* ob = (uint4*)(outp + (size_t)row*Dq + c0);
  ob[0] = make_uint4(w[0],w[1],w[2],w[3]);
  ob[1] = make_uint4(w[4],w[5],w[6],w[7]);
}

// ================= 256x256 8-wave 5-phase NT GEMM (K=1024), persistent tiles ====
// (R10-proven schedule.)  EPI 0: qkv (consume LN stats)  EPI 1: resid-add (produce)
// EPI 2: gelu-w1 (consume)
template<int EPI>
__global__ __launch_bounds__(512, 2) void gemm_nt2(
    const u16* __restrict__ A, int lda,
    const u16* __restrict__ Bt, int ldb,
    void* __restrict__ Cout, const u16* __restrict__ resid,
    const float* __restrict__ bias, int ldc,
    const float2* __restrict__ pstat_in, int nchunk,
    const float* __restrict__ uvp, float2* __restrict__ pstat_out,
    int total, int gxT)
{
  __shared__ u16 lds[65536];
  int tid = threadIdx.x, lane = tid & 63;
  int wave = tid >> 6;
  int wm = wave >> 2, wn = wave & 3;
  int l15 = lane & 15, l4 = lane >> 4;
  int swz = (l15 & 7) << 4;

  int srow = tid >> 3, scolb = (tid & 7) * 16;
  int scolx = scolb ^ ((srow & 7) << 4);

  for(int w = blockIdx.x; w < total; w += gridDim.x){
    int qq = total >> 3, rr = total & 7;
    int xcd = w & 7, idx = w >> 3;
    int wgid = (xcd < rr ? xcd*(qq+1) : rr*(qq+1) + (xcd-rr)*qq) + idx;
    int bx = wgid % gxT, by = wgid / gxT;
    int m0 = by*256, n0 = bx*256;

    auto stage2 = [&](int d, int kt, int h){
      #pragma unroll
      for(int cc=0; cc<2; cc++){
        int c = 2*h + cc;
        if(c < 4){
          int row = c*64 + srow;
          const u16* src = A + (size_t)(m0+row)*lda + kt*64 + (scolx>>1);
          GLOAD_LDS16(src, &lds[d*16384 + c*4096 + tid*8]);
        } else {
          int c4 = c - 4;
          int row = c4*64 + srow;
          const u16* src = Bt + (size_t)(n0+row)*ldb + kt*64 + (scolx>>1);
          GLOAD_LDS16(src, &lds[32768 + d*16384 + c4*4096 + tid*8]);
        }
      }
    };
    auto rdA = [&](int d, int i, int s)->bf16x8{
      int row = wm*128 + i*16 + l15;
      int byt = row*128 + ((s*64 + l4*16) ^ swz);
      return *(const bf16x8*)((const char*)lds + d*32768 + byt);
    };
    auto rdB = [&](int d, int n, int s)->bf16x8{
      int row = wn*64 + n*16 + l15;
      int byt = row*128 + ((s*64 + l4*16) ^ swz);
      return *(const bf16x8*)((const char*)lds + 65536 + d*32768 + byt);
    };

    f32x4 acc[8][4] = {};

    __syncthreads();
    #pragma unroll
    for(int h=0;h<4;h++) stage2(0, 0, h);

    for(int t=0; t<16; ++t){
      int d = t & 1;
      bf16x8 bfr[4][2];
      if(t < 15){
        stage2(d^1, t+1, 0);
        asm volatile("s_waitcnt vmcnt(2)" ::: "memory");
      } else {
        asm volatile("s_waitcnt vmcnt(0)" ::: "memory");
      }
      __builtin_amdgcn_sched_barrier(0);
      __builtin_amdgcn_s_barrier();
      bfr[0][0]=rdB(d,0,0); bfr[0][1]=rdB(d,0,1);
      bfr[1][0]=rdB(d,1,0); bfr[1][1]=rdB(d,1,1);
      bf16x8 a0s0=rdA(d,0,0), a0s1=rdA(d,0,1), a1s0=rdA(d,1,0), a1s1=rdA(d,1,1);
      __builtin_amdgcn_s_setprio(1);
      acc[0][0]=MFMA16(a0s0,bfr[0][0],acc[0][0]); acc[0][0]=MFMA16(a0s1,bfr[0][1],acc[0][0]);
      acc[0][1]=MFMA16(a0s0,bfr[1][0],acc[0][1]); acc[0][1]=MFMA16(a0s1,bfr[1][1],acc[0][1]);
      acc[1][0]=MFMA16(a1s0,bfr[0][0],acc[1][0]); acc[1][0]=MFMA16(a1s1,bfr[0][1],acc[1][0]);
      acc[1][1]=MFMA16(a1s0,bfr[1][0],acc[1][1]); acc[1][1]=MFMA16(a1s1,bfr[1][1],acc[1][1]);
      __builtin_amdgcn_s_setprio(0);
      __builtin_amdgcn_s_barrier();
      bfr[2][0]=rdB(d,2,0); bfr[2][1]=rdB(d,2,1);
      bfr[3][0]=rdB(d,3,0); bfr[3][1]=rdB(d,3,1);
      if(t < 15) stage2(d^1, t+1, 1);
      __builtin_amdgcn_s_barrier();
      __builtin_amdgcn_s_setprio(1);
      acc[0][2]=MFMA16(a0s0,bfr[2][0],acc[0][2]); acc[0][2]=MFMA16(a0s1,bfr[2][1],acc[0][2]);
      acc[0][3]=MFMA16(a0s0,bfr[3][0],acc[0][3]); acc[0][3]=MFMA16(a0s1,bfr[3][1],acc[0][3]);
      acc[1][2]=MFMA16(a1s0,bfr[2][0],acc[1][2]); acc[1][2]=MFMA16(a1s1,bfr[2][1],acc[1][2]);
      acc[1][3]=MFMA16(a1s0,bfr[3][0],acc[1][3]); acc[1][3]=MFMA16(a1s1,bfr[3][1],acc[1][3]);
      __builtin_amdgcn_s_setprio(0);
      __builtin_amdgcn_s_barrier();
      #pragma unroll
      for(int q=1;q<4;q++){
        bf16x8 c0s0=rdA(d,2*q,0), c0s1=rdA(d,2*q,1), c1s0=rdA(d,2*q+1,0), c1s1=rdA(d,2*q+1,1);
        if(t < 15 && q < 3) stage2(d^1, t+1, q+1);
        __builtin_amdgcn_s_barrier();
        __builtin_amdgcn_s_setprio(1);
        #pragma unroll
        for(int n=0;n<4;n++){
          acc[2*q][n]   = MFMA16(c0s0, bfr[n][0], acc[2*q][n]);
          acc[2*q][n]   = MFMA16(c0s1, bfr[n][1], acc[2*q][n]);
          acc[2*q+1][n] = MFMA16(c1s0, bfr[n][0], acc[2*q+1][n]);
          acc[2*q+1][n] = MFMA16(c1s1, bfr[n][1], acc[2*q+1][n]);
        }
        __builtin_amdgcn_s_setprio(0);
        __builtin_amdgcn_s_barrier();
      }
    }

    // ---- epilogue ----
    if constexpr (EPI == 1){
      float2* statsS = (float2*)((char*)lds + 49152);
      float* slotf = (float*)((char*)lds + wave*4096);
      float bv[4];
      #pragma unroll
      for(int n=0;n<4;n++) bv[n] = bias ? bias[n0 + wn*64 + n*16 + l15] : 0.f;
      #pragma unroll
      for(int i=0;i<8;i++){
        #pragma unroll
        for(int n=0;n<4;n++)
          #pragma unroll
          for(int r=0;r<4;r++)
            slotf[(l4*4+r)*64 + n*16 + l15] = acc[i][n][r] + bv[n];
        #pragma unroll
        for(int st=0;st<2;st++){
          int u = st*64 + lane;
          int row = u >> 3, c8 = (u & 7)*8;
          f32x4 lo = *(const f32x4*)&slotf[row*64 + c8];
          f32x4 hi = *(const f32x4*)&slotf[row*64 + c8 + 4];
          size_t o = (size_t)(m0 + wm*128 + i*16 + row)*ldc + n0 + wn*64 + c8;
          bf16x8 rb = *(const bf16x8*)(resid + o);
          bf16x8 ov; float fs=0.f, fq=0.f;
          #pragma unroll
          for(int j=0;j<4;j++){
            float a_ = lo[j] + bf2f((u16)rb[j]);
            float b_ = hi[j] + bf2f((u16)rb[4+j]);
            ov[j]   = (short)f2bf(a_);
            ov[4+j] = (short)f2bf(b_);
            fs += a_ + b_; fq += a_*a_ + b_*b_;
          }
          *(bf16x8*)((u16*)Cout + o) = ov;
          fs += __shfl_xor(fs,1); fq += __shfl_xor(fq,1);
          fs += __shfl_xor(fs,2); fq += __shfl_xor(fq,2);
          fs += __shfl_xor(fs,4); fq += __shfl_xor(fq,4);
          if((lane&7)==0){
            float2 pp; pp.x=fs; pp.y=fq;
            statsS[(wm*128 + i*16 + st*8 + (lane>>3))*4 + wn] = pp;
          }
        }
      }
      __syncthreads();
      if(tid < 256){
        float S=0.f, Q=0.f;
        #pragma unroll
        for(int w2_=0;w2_<4;w2_++){ float2 pp = statsS[tid*4+w2_]; S+=pp.x; Q+=pp.y; }
        float2 pp; pp.x=S; pp.y=Q;
        pstat_out[(size_t)bx*Mq + m0 + tid] = pp;
      }
    } else {
      float2* lstat = (float2*)((char*)lds + 49152);
      if(tid < 256){
        float S=0.f, Q=0.f;
        for(int c=0;c<nchunk;c++){ float2 pp = pstat_in[(size_t)c*Mq + m0 + tid]; S+=pp.x; Q+=pp.y; }
        float mean = S*(1.f/1024.f);
        float var  = Q*(1.f/1024.f) - mean*mean;
        float2 sm; sm.x = rsqrtf(var + 1e-5f); sm.y = mean;
        lstat[tid] = sm;
      }
      __syncthreads();
      u16* slot = (u16*)((char*)lds + wave*2048);
      float uvv[4][2], bv[4];
      #pragma unroll
      for(int n=0;n<4;n++){
        int ncol = n0 + wn*64 + n*16 + l15;
        float2 uv2 = ((const float2*)uvp)[ncol];
        uvv[n][0] = uv2.x; uvv[n][1] = uv2.y;
        if constexpr (EPI == 2) bv[n] = bias[ncol];
      }
      #pragma unroll
      for(int i=0;i<8;i++){
        #pragma unroll
        for(int n=0;n<4;n++)
          #pragma unroll
          for(int r=0;r<4;r++){
            float2 sm = lstat[wm*128 + i*16 + l4*4 + r];
            float va = sm.x*acc[i][n][r] - sm.x*sm.y*uvv[n][0] + uvv[n][1];
            u16 ov;
            if constexpr (EPI == 0){
              ov = f2bf(va);
            } else {
              float xg = va + bv[n];
              float tg = tanhf(0.79788456080286536f*(xg + 0.044715f*xg*xg*xg));
              ov = f2bf(0.5f*xg*(1.f+tg));
            }
            slot[(l4*4+r)*64 + n*16 + l15] = ov;
          }
        #pragma unroll
        for(int st=0;st<2;st++){
          int u = st*64 + lane;
          int row = u >> 3, c8 = (u & 7)*8;
          bf16x8 v8 = *(const bf16x8*)&slot[row*64 + c8];
          *(bf16x8*)((u16*)Cout + (size_t)(m0 + wm*128 + i*16 + row)*ldc + n0 + wn*64 + c8) = v8;
        }
      }
    }
  }
}

// Head GEMM v3: M=128 tile, grid (8,2,49)=784 blocks (~3/CU), software-pipelined.
__global__ __launch_bounds__(256, 3) void gemm_head(
    const u16* __restrict__ A, const float* __restrict__ W,
    u16* __restrict__ parts)
{
  __shared__ u16 sA[2][128*32];   // 2 x 8 KB double-buffered A tiles
  int tid = threadIdx.x, lane = tid & 63;
  int wave = tid >> 6;
  int wm = wave >> 1, wn = wave & 1;
  int l15 = lane & 15, l4 = lane >> 4;
  int bx = blockIdx.x, by = blockIdx.y, z = blockIdx.z;
  int n0 = bx*128, m0 = by*128;
  size_t abase = (size_t)m0*KHEADq + (size_t)z*1024;
  f32x4 acc[4][4] = {};
  const float* wp = W + ((size_t)z*1024 + (size_t)l4*8)*1024 + n0 + wn*64 + l15;

  auto stageA = [&](int d, int kt){
    #pragma unroll
    for(int c=0;c<2;c++){
      int s2 = c*256+tid;
      GLOAD_LDS16(A + abase + (size_t)(s2>>2)*KHEADq + kt*32 + (s2&3)*8, &sA[d][s2*8]);
    }
  };
  float wA[4][8], wB[4][8];
  auto loadW = [&](float (&dst)[4][8], int kt){
    #pragma unroll
    for(int f=0;f<4;f++)
      #pragma unroll
      for(int jj=0;jj<8;jj++)
        dst[f][jj] = wp[(size_t)(kt*32+jj)*1024 + f*16];
  };
  auto compute = [&](int d, float (&wreg)[4][8]){
    bf16x8 bfr[4];
    #pragma unroll
    for(int f=0;f<4;f++){
      bf16x8 bv;
      #pragma unroll
      for(int jj=0;jj<8;jj++)
        bv[jj] = __builtin_bit_cast(short, __float2bfloat16(wreg[f][jj]));
      bfr[f] = bv;
    }
    bf16x8 af[4];
    #pragma unroll
    for(int i=0;i<4;i++)
      af[i] = *(const bf16x8*)&sA[d][(wm*64 + i*16 + l15)*32 + l4*8];
    #pragma unroll
    for(int i=0;i<4;i++)
      #pragma unroll
      for(int j=0;j<4;j++)
        acc[i][j] = MFMA16(af[i], bfr[j], acc[i][j]);
  };

  stageA(0, 0);
  loadW(wA, 0);
  for(int k2=0; k2<16; ++k2){
    int kt = 2*k2;
    stageA(1, kt+1);
    loadW(wB, kt+1);
    asm volatile("s_waitcnt vmcnt(34)" ::: "memory");
    __builtin_amdgcn_s_barrier();
    compute(0, wA);
    __builtin_amdgcn_s_barrier();
    if(k2 < 15){
      stageA(0, kt+2);
      loadW(wA, kt+2);
      asm volatile("s_waitcnt vmcnt(34)" ::: "memory");
    } else {
      asm volatile("s_waitcnt vmcnt(0)" ::: "memory");
    }
    __builtin_amdgcn_s_barrier();
    compute(1, wB);
    __builtin_amdgcn_s_barrier();
  }

  u16* slot = &sA[0][wave*1024];
  u16* base = parts + (size_t)z*(Bq*1024);
  #pragma unroll
  for(int i=0;i<4;i++){
    #pragma unroll
    for(int j=0;j<4;j++)
      #pragma unroll
      for(int rr=0;rr<4;rr++)
        slot[(l4*4+rr)*64 + j*16 + l15] = f2bf(acc[i][j][rr]);
    #pragma unroll
    for(int st=0;st<2;st++){
      int u = st*64 + lane;
      int row = u >> 3, c8 = (u & 7)*8;
      bf16x8 v8 = *(const bf16x8*)&slot[row*64 + c8];
      *(bf16x8*)(base + (size_t)(m0 + wm*64 + i*16 + row)*1024 + n0 + wn*64 + c8) = v8;
    }
  }
}

// Fused attention per (b,h); wave-parallel softmax; V staged in LDS (two halves).
__global__ __launch_bounds__(256) void attn_kernel(u16* __restrict__ qkv)
{
  __shared__ float sS[64][65];
  __shared__ u16 sP[64][64];
  __shared__ __align__(16) u16 sV[64*260 + 4];
  int bh = blockIdx.x;
  int b = bh >> 1, h = bh & 1;
  int tid = threadIdx.x, lane = tid & 63, wave = tid >> 6;
  int l15 = lane & 15, l4 = lane >> 4;
  f32x4 zero4 = {0.f,0.f,0.f,0.f};
  bf16x8 zb = {0,0,0,0,0,0,0,0};
  f32x4 acc[4];
  #pragma unroll
  for(int i=0;i<4;i++) acc[i] = zero4;
  int srow = wave*16 + l15;
  const u16* qp = qkv + (size_t)(b*Sq + srow)*STq + h*HDq + l4*8;
  const u16* kbase = qkv + (size_t)b*Sq*STq + Dq + h*HDq + l4*8;
  for(int kt=0;kt<16;kt++){
    bf16x8 aq = (srow < Sq) ? *(const bf16x8*)(qp + kt*32) : zb;
    #pragma unroll
    for(int fn=0;fn<4;fn++){
      int s2 = fn*16 + l15;
      bf16x8 bk = (s2 < Sq) ? *(const bf16x8*)(kbase + (size_t)s2*STq + kt*32) : zb;
      acc[fn] = MFMA16(aq, bk, acc[fn]);
    }
  }
  const float scale = 0.04419417382415922f; // 1/sqrt(512)
  #pragma unroll
  for(int fn=0;fn<4;fn++)
    #pragma unroll
    for(int r=0;r<4;r++)
      sS[wave*16 + l4*4 + r][fn*16 + l15] = acc[fn][r]*scale;
  const u16* vsrc = qkv + (size_t)b*Sq*STq + 2*Dq + h*HDq;
  #pragma unroll
  for(int p=0;p<16;p++){
    int i = p*256 + tid;
    int row = i >> 6, ch = i & 63;
    uint2 v2 = (row < Sq) ? *(const uint2*)(vsrc + (size_t)row*STq + ch*4) : make_uint2(0u,0u);
    *(uint2*)&sV[row*260 + ch*4] = v2;
  }
  __syncthreads();
  {
    int r = tid >> 2, qd = tid & 3;
    float mx = -1e30f;
    for(int j=qd;j<Sq;j+=4) mx = fmaxf(mx, sS[r][j]);
    mx = fmaxf(mx, __shfl_xor(mx,1));
    mx = fmaxf(mx, __shfl_xor(mx,2));
    float sum = 0.f;
    for(int j=qd;j<Sq;j+=4){ float e = __expf(sS[r][j]-mx); sS[r][j]=e; sum+=e; }
    sum += __shfl_xor(sum,1);
    sum += __shfl_xor(sum,2);
    float inv = 1.f/sum;
    for(int j=qd;j<64;j+=4) sP[r][j] = (j<Sq)? f2bf(sS[r][j]*inv) : (u16)0;
  }
  uint2 vreg[16];
  #pragma unroll
  for(int p=0;p<16;p++){
    int i = p*256 + tid;
    int row = i >> 6, ch = i & 63;
    vreg[p] = (row < Sq) ? *(const uint2*)(vsrc + 256 + (size_t)row*STq + ch*4) : make_uint2(0u,0u);
  }
  __syncthreads();
  bf16x8 ap[2];
  #pragma unroll
  for(int kt2=0;kt2<2;kt2++)
    ap[kt2] = *(const bf16x8*)&sP[wave*16 + l15][kt2*32 + l4*8];
  u16* cb = qkv + (size_t)b*Sq*STq + h*HDq;
  for(int fn=0;fn<16;fn++){
    f32x4 c4 = zero4;
    #pragma unroll
    for(int kt2=0;kt2<2;kt2++){
      int rbase = kt2*32 + l4*8;
      bf16x8 bv;
      #pragma unroll
      for(int jj=0;jj<8;jj++) bv[jj] = (short)sV[(rbase+jj)*260 + fn*16 + l15];
      c4 = MFMA16(ap[kt2], bv, c4);
    }
    #pragma unroll
    for(int r=0;r<4;r++){
      int s = wave*16 + l4*4 + r;
      if(s < Sq) cb[(size_t)s*STq + fn*16 + l15] = f2bf(c4[r]);
    }
  }
  __syncthreads();
  #pragma unroll
  for(int p=0;p<16;p++){
    int i = p*256 + tid;
    int row = i >> 6, ch = i & 63;
    *(uint2*)&sV[row*260 + ch*4] = vreg[p];
  }
  __syncthreads();
  for(int fn=16;fn<32;fn++){
    f32x4 c4 = zero4;
    #pragma unroll
    for(int kt2=0;kt2<2;kt2++){
      int rbase = kt2*32 + l4*8;
      bf16x8 bv;
      #pragma unroll
      for(int jj=0;jj<8;jj++) bv[jj] = (short)sV[(rbase+jj)*260 + (fn-16)*16 + l15];
      c4 = MFMA16(ap[kt2], bv, c4);
    }
    #pragma unroll
    for(int r=0;r<4;r++){
      int s = wave*16 + l4*4 + r;
      if(s < Sq) cb[(size_t)s*STq + fn*16 + l15] = f2bf(c4[r]);
    }
  }
}

__global__ __launch_bounds__(256) void head_finalize(const u16* __restrict__ parts,
    const float* __restrict__ hb, float* __restrict__ outp){
  int idx = blockIdx.x*256 + threadIdx.x;
  float s = hb[idx & 1023];
  #pragma unroll
  for(int z=0;z<49;z++) s += bf2f(parts[(size_t)z*(Bq*1024) + idx]);
  outp[idx] = fmaxf(s, 0.f);
}

extern "C" void kernel_launch(void* const* d_in, const int* in_sizes, int n_in,
                              void* d_out, int out_size, void* d_ws, size_t ws_size,
                              hipStream_t stream) {
  (void)in_sizes; (void)n_in; (void)out_size;
  const float* x    = (const float*)d_in[0];
  const float* pos  = (const float*)d_in[1];
  const float* ln1s = (const float*)d_in[2];
  const float* ln1b = (const float*)d_in[3];
  const float* wq   = (const float*)d_in[4];
  const float* wk   = (const float*)d_in[5];
  const float* wv   = (const float*)d_in[6];
  const float* wo   = (const float*)d_in[7];
  const float* ln2s = (const float*)d_in[8];
  const float* ln2b = (const float*)d_in[9];
  const float* w1   = (const float*)d_in[10];
  const float* b1   = (const float*)d_in[11];
  const float* w2   = (const float*)d_in[12];
  const float* b2   = (const float*)d_in[13];
  const float* lnfs = (const float*)d_in[14];
  const float* lnfb = (const float*)d_in[15];
  const float* hw   = (const float*)d_in[16];
  const float* hb   = (const float*)d_in[17];
  float* out = (float*)d_out;

  char* ws = (char*)d_ws;
  size_t off = 0;
  auto carve = [&](size_t n) -> char* { char* p = ws + off; off += (n + 255) & ~(size_t)255; return p; };
  u16*   h     = (u16*)  carve((size_t)Mq*Dq*2);
  u16*   act0  = (u16*)  carve((size_t)Mq*Dq*2);
  u16*   act1  = (u16*)  carve((size_t)Mq*Dq*2);
  u16*   qkv   = (u16*)  carve((size_t)(Mq+16)*STq*2);
  u16*   wT    = (u16*)  carve((size_t)12*Dq*Dq*2);
  float2* pstat= (float2*)carve((size_t)8*Mq*sizeof(float2));
  float* uvbuf = (float*)carve((size_t)2*4096*2*4);
  u16*   parts = qkv;   // head partials (bf16, 25.7 MB) alias qkv (dead by head time)
  if (off > ws_size) return;

  setup_kernel<<<14592, 256, 0, stream>>>(x, pos, h, pstat, qkv,
      wq, wk, wv, wo, w1, w2, ln1s, ln1b, ln2s, ln2b, wT, uvbuf);

  for(int l=0;l<2;l++){
    u16* qkvT = wT + (size_t)(l*6+0)*Dq*Dq;
    u16* woT  = wT + (size_t)(l*6+3)*Dq*Dq;
    u16* w1T  = wT + (size_t)(l*6+4)*Dq*Dq;
    u16* w2T  = wT + (size_t)(l*6+5)*Dq*Dq;
    const float* uvq = uvbuf + (size_t)l*8192;
    const float* uv1 = uvbuf + (size_t)l*8192 + 3072*2;

    gemm_nt2<0><<<512, 512, 0, stream>>>(h, Dq, qkvT, Dq, qkv, nullptr, nullptr, STq,
                                         pstat, (l==0)?8:4, uvq, nullptr, 588, 12);
    attn_kernel<<<Bq*Hq, 256, 0, stream>>>(qkv);
    gemm_nt2<1><<<196, 512, 0, stream>>>(qkv, STq, woT, Dq, h, h, nullptr, Dq,
                                         nullptr, 0, nullptr, pstat, 196, 4);
    gemm_nt2<2><<<196, 512, 0, stream>>>(h, Dq, w1T, Dq, act1, nullptr, b1 + l*Dq, Dq,
                                         pstat, 4, uv1, nullptr, 196, 4);
    gemm_nt2<1><<<196, 512, 0, stream>>>(act1, Dq, w2T, Dq, h, h, b2 + l*Dq, Dq,
                                         nullptr, 0, nullptr, pstat, 196, 4);
  }

  ln_kernel<<<Mq/4, 256, 0, stream>>>(h, lnfs, lnfb, act0);
  gemm_head<<<dim3(8,2,49), 256, 0, stream>>>(act0, hw, parts);
  head_finalize<<<1024, 256, 0, stream>>>(parts, hb, out);
}